// Round 7
// baseline (170.395 us; speedup 1.0000x reference)
//
#include <hip/hip_runtime.h>

// Problem constants
constexpr int BB  = 4;     // batch
constexpr int SEQ = 2048;  // sequence length
constexpr int CC  = 384;   // model dim
constexpr int C3  = 1152;  // 3*C
constexpr int NH  = 12;    // heads
constexpr int HD  = 32;    // head dim
constexpr float SCALE = 0.17677669529663689f;  // 32^-0.5
constexpr float LOG2E = 1.4426950408889634f;
constexpr float KSC   = SCALE * LOG2E;         // folded into K at qkv epilogue
constexpr size_t KV_BYTES = (size_t)2 * BB * NH * SEQ * HD * 2;
constexpr size_t WT_BYTES = ((size_t)C3 * CC + (size_t)CC * CC) * 2;
constexpr size_t XB_BYTES = (size_t)BB * SEQ * CC * 2;

typedef __attribute__((ext_vector_type(8))) short short8_t;    // 8 bf16 (16 B)
typedef __attribute__((ext_vector_type(4))) float floatx4;     // MFMA C/D

#if __has_builtin(__builtin_amdgcn_exp2f)
#define EXP2F __builtin_amdgcn_exp2f
#else
#define EXP2F __builtin_exp2f
#endif

__device__ __forceinline__ unsigned short f2bf(float f) {
    unsigned int u = __builtin_bit_cast(unsigned int, f);
    u += 0x7fffu + ((u >> 16) & 1u);   // RNE
    return (unsigned short)(u >> 16);
}
// Round-nearest bf16 pair pack: 2 adds + 1 perm, all full-rate.
__device__ __forceinline__ unsigned int pk_rn(float lo, float hi) {
    return __builtin_amdgcn_perm(__builtin_bit_cast(unsigned int, hi) + 0x8000u,
                                 __builtin_bit_cast(unsigned int, lo) + 0x8000u,
                                 0x07060302u);
}
// Single-op RNE bf16 pair pack for the attn hot loop (gfx950 VOP3).
__device__ __forceinline__ unsigned int cvtpk(float lo, float hi) {
    unsigned int r;
    asm("v_cvt_pk_bf16_f32 %0, %1, %2" : "=v"(r) : "v"(lo), "v"(hi));
    return r;
}
__device__ __forceinline__ short8_t pack8(float4 a, float4 b) {
    uint4 u;
    u.x = pk_rn(a.x, a.y); u.y = pk_rn(a.z, a.w);
    u.z = pk_rn(b.x, b.y); u.w = pk_rn(b.z, b.w);
    return __builtin_bit_cast(short8_t, u);
}

// ---------------------------------------------------------------------------
// K0: prep. bid<144: transpose W_qkv/W_proj to bf16 [n][k] (stride CC).
// bid>=144: convert x to bf16 row-major.
// ---------------------------------------------------------------------------
__global__ __launch_bounds__(256) void prep_kernel(
    const float* __restrict__ x, const float* __restrict__ wqkv,
    const float* __restrict__ wproj,
    unsigned short* __restrict__ wqkvT, unsigned short* __restrict__ wprojT,
    unsigned short* __restrict__ xb)
{
    const int bid = blockIdx.x;
    if (bid >= 144) {                  // x -> bf16, 2048 elems per block
        const size_t base = (size_t)(bid - 144) * 2048 + threadIdx.x * 8;
        const float4 a = *(const float4*)(x + base);
        const float4 b = *(const float4*)(x + base + 4);
        uint4 u;
        u.x = pk_rn(a.x, a.y); u.y = pk_rn(a.z, a.w);
        u.z = pk_rn(b.x, b.y); u.w = pk_rn(b.z, b.w);
        *(uint4*)(xb + base) = u;
        return;
    }
    __shared__ float ls[64][68];
    const float* src; unsigned short* dst; int SN, k0, n0;
    if (bid < 108) {                   // Wqkv: 6 k-tiles x 18 n-tiles
        src = wqkv; dst = wqkvT; SN = C3;
        k0 = (bid / 18) * 64; n0 = (bid % 18) * 64;
    } else {                           // Wproj: 6 x 6
        const int b2 = bid - 108;
        src = wproj; dst = wprojT; SN = CC;
        k0 = (b2 / 6) * 64; n0 = (b2 % 6) * 64;
    }
    const int t  = threadIdx.x;
    const int rr = t >> 4, cc4 = (t & 15) * 4;
#pragma unroll
    for (int p = 0; p < 4; ++p) {
        const int row = p * 16 + rr;
        const float4 v = *(const float4*)&src[(size_t)(k0 + row) * SN + n0 + cc4];
        ls[row][cc4] = v.x; ls[row][cc4 + 1] = v.y;
        ls[row][cc4 + 2] = v.z; ls[row][cc4 + 3] = v.w;
    }
    __syncthreads();
#pragma unroll
    for (int p = 0; p < 4; ++p) {
        const int nrow = p * 16 + rr;
        uint2 u;
        u.x = pk_rn(ls[cc4][nrow],     ls[cc4 + 1][nrow]);
        u.y = pk_rn(ls[cc4 + 2][nrow], ls[cc4 + 3][nrow]);
        *(uint2*)&dst[(size_t)(n0 + nrow) * CC + k0 + cc4] = u;
    }
}

// ---------------------------------------------------------------------------
// K1: qkv = x @ W_qkv. R18-passing structure (128m x 128n, grid 576, dbuf
// LDS staging, direct b128 A loads from xb). R19 epilogue: Q written BF16 to
// qb; K pre-scaled by SCALE*LOG2E. R24: V written in MFMA-fragment-PERMUTED
// chunk order (key k -> pos ((k&15)>>2)*8 + (k>=16)*4 + (k&3) within each
// 32-key chunk) so attn's PV A-operand is a single b128 global load —
// enables the barrier-free attn. sc%4==0 keeps the uint2 write contiguous.
// ---------------------------------------------------------------------------
__global__ __launch_bounds__(256) void qkv_fast(
    const unsigned short* __restrict__ xb,
    const unsigned short* __restrict__ wT,   // WqkvT bf16 [1152][384]
    unsigned short* __restrict__ qb,         // d_out as bf16 [B*S][C]
    unsigned short* __restrict__ kv)
{
    __shared__ __align__(16) unsigned short As[2][128][40];  // 20480 B
    __shared__ __align__(16) unsigned short Bs[2][128][40];  // 20480 B

    const int mt   = blockIdx.x & 63;
    const int nb   = blockIdx.x >> 6;
    const int tid  = threadIdx.x;
    const int wid  = tid >> 6;
    const int lane = tid & 63;
    const int quad = lane >> 4;
    const int col  = lane & 15;
    const int wr   = wid >> 1, wc = wid & 1;
    const int m0 = mt * 128, n0 = nb * 128;

    const int arow = tid >> 1;
    const int aoff = (tid & 1) * 16;

    floatx4 acc[4][4];
#pragma unroll
    for (int i = 0; i < 4; ++i)
#pragma unroll
        for (int j = 0; j < 4; ++j) acc[i][j] = (floatx4){0.f, 0.f, 0.f, 0.f};

    const unsigned short* xrow = xb + (size_t)(m0 + arow) * CC + aoff;
    const unsigned short* wrow = wT + (size_t)(n0 + arow) * CC + aoff;

    short8_t ast0, ast1, bst0, bst1;
    ast0 = *(const short8_t*)xrow;
    ast1 = *(const short8_t*)(xrow + 8);
    bst0 = *(const short8_t*)wrow;
    bst1 = *(const short8_t*)(wrow + 8);
    *(short8_t*)&As[0][arow][aoff]     = ast0;
    *(short8_t*)&As[0][arow][aoff + 8] = ast1;
    *(short8_t*)&Bs[0][arow][aoff]     = bst0;
    *(short8_t*)&Bs[0][arow][aoff + 8] = bst1;

    for (int it = 0; it < CC / 32; ++it) {
        const int kn = (it + 1 < CC / 32) ? (it + 1) * 32 : 0;  // wrap harmless
        ast0 = *(const short8_t*)(xrow + kn);
        ast1 = *(const short8_t*)(xrow + kn + 8);
        bst0 = *(const short8_t*)(wrow + kn);
        bst1 = *(const short8_t*)(wrow + kn + 8);

        __syncthreads();
        const int p = it & 1;
        short8_t af[4], bf[4];
#pragma unroll
        for (int i = 0; i < 4; ++i)
            af[i] = *(const short8_t*)&As[p][wr * 64 + i * 16 + col][quad * 8];
#pragma unroll
        for (int j = 0; j < 4; ++j)
            bf[j] = *(const short8_t*)&Bs[p][wc * 64 + j * 16 + col][quad * 8];
#pragma unroll
        for (int j = 0; j < 4; ++j)
#pragma unroll
            for (int i = 0; i < 4; ++i)
                acc[i][j] = __builtin_amdgcn_mfma_f32_16x16x32_bf16(af[i], bf[j], acc[i][j], 0, 0, 0);

        *(short8_t*)&As[p ^ 1][arow][aoff]     = ast0;
        *(short8_t*)&As[p ^ 1][arow][aoff + 8] = ast1;
        *(short8_t*)&Bs[p ^ 1][arow][aoff]     = bst0;
        *(short8_t*)&Bs[p ^ 1][arow][aoff + 8] = bst1;
    }

    const int t = nb / 3;              // 0:q 1:k 2:v (uniform per block)
#pragma unroll
    for (int i = 0; i < 4; ++i) {
        const int mg = m0 + wr * 64 + i * 16 + quad * 4;
        if (t == 0) {
#pragma unroll
            for (int j = 0; j < 4; ++j) {
                const int n = n0 + wc * 64 + j * 16 + col;
#pragma unroll
                for (int r = 0; r < 4; ++r)
                    qb[(size_t)(mg + r) * CC + n] = f2bf(acc[i][j][r]);
            }
        } else if (t == 1) {
            const int b = mg >> 11, s = mg & (SEQ - 1);
#pragma unroll
            for (int j = 0; j < 4; ++j) {
                const int rem = n0 - CC + wc * 64 + j * 16 + col;
                const int h = rem >> 5, d = rem & 31;
                unsigned short* kp = kv + ((size_t)(b * NH + h) * SEQ + s) * HD + d;
#pragma unroll
                for (int r = 0; r < 4; ++r)
                    kp[(size_t)r * HD] = f2bf(acc[i][j][r] * KSC);  // pre-scaled
            }
        } else {
            const int b = mg >> 11, s = mg & (SEQ - 1);
            const int sc = s & 31;     // sc % 4 == 0 by construction
            const int pos = ((sc & 15) >> 2) * 8 + ((sc >= 16) ? 4 : 0);
            const int sperm = (s & ~31) + pos;    // permuted key position
            unsigned short* vtb = kv + (size_t)BB * NH * SEQ * HD;
#pragma unroll
            for (int j = 0; j < 4; ++j) {
                const int rem = n0 - 2 * CC + wc * 64 + j * 16 + col;
                const int h = rem >> 5, d = rem & 31;
                uint2 u;
                u.x = pk_rn(acc[i][j][0], acc[i][j][1]);
                u.y = pk_rn(acc[i][j][2], acc[i][j][3]);
                *(uint2*)&vtb[((size_t)(b * NH + h) * HD + d) * SEQ + sperm] = u;
            }
        }
    }
}

// ---------------------------------------------------------------------------
// K2: MFMA flash attention — R24: BARRIER-FREE, ZERO-LDS.
// R23 post-mortem: 64-row blocks doubled redundant K/V work per useful FLOP
// (attn 42->63us) — amortization beats occupancy. Reverted to 128 q-rows,
// t=2 per wave, grid 768 (3 blocks/CU).
// R24: V LDS pipeline eliminated. qkv writes V pre-permuted into MFMA
// fragment order, so each V fragment is ONE b128 global load (16 fully-
// consumed 64B lines/wave, L1/L2-resident — same pattern K uses since R22).
// No __syncthreads remain: 12 waves/CU drift freely, VMEM gathers of one
// wave overlap MFMA/exp of the others (the barrier drain was blocking this).
// kaf/vaf refilled per-chunk right after last use (~full iter of latency).
// ---------------------------------------------------------------------------
__global__ __launch_bounds__(256, 3) void attn_kernel(
    const unsigned short* __restrict__ kv,
    const unsigned short* __restrict__ qb,   // bf16 Q [B*S][C] (d_out)
    unsigned short* __restrict__ ab)         // bf16 att [B*S][C] (= xb space)
{
    const int bid  = blockIdx.x;
    const int qp   = bid / 48;
    const int bh   = bid % 48;
    const int h    = bh % NH;
    const int b    = bh / NH;
    const int w    = threadIdx.x >> 6;
    const int lane = threadIdx.x & 63;
    const int quad = lane >> 4;
    const int col  = lane & 15;

    const unsigned short* K  = kv + (size_t)bh * SEQ * HD;
    const unsigned short* VT = kv + (size_t)BB * NH * SEQ * HD + (size_t)bh * HD * SEQ;

    // per-thread fragment bases
    const unsigned short* Kf  = K + (size_t)col * HD + quad * 8;
    const unsigned short* Vf0 = VT + (size_t)col * SEQ + quad * 8;         // dims 0-15
    const unsigned short* Vf1 = VT + (size_t)(16 + col) * SEQ + quad * 8;  // dims 16-31

    int qrow[2];
    short8_t qf[2];
#pragma unroll
    for (int t = 0; t < 2; ++t) {
        qrow[t] = b * SEQ + qp * 128 + (w + 4 * t) * 16 + col;
        qf[t] = *(const short8_t*)(qb + (size_t)qrow[t] * CC + h * HD + quad * 8);
    }

    short8_t ones;
#pragma unroll
    for (int e = 0; e < 8; ++e) ones[e] = (short)0x3F80;

    floatx4 o[2][2];
    floatx4 lacc[2];
#pragma unroll
    for (int t = 0; t < 2; ++t) {
        lacc[t] = (floatx4){0.f, 0.f, 0.f, 0.f};
#pragma unroll
        for (int i = 0; i < 2; ++i) o[t][i] = (floatx4){0.f, 0.f, 0.f, 0.f};
    }
    const float ci = -10.f * LOG2E;
    const floatx4 cinit = {ci, ci, ci, ci};

    // prologue: K and V fragments for tile 0 -> registers
    short8_t kaf[4][2], vaf[4][2];
#pragma unroll
    for (int c = 0; c < 4; ++c) {
        kaf[c][0] = *(const short8_t*)(Kf + (size_t)(c * 32) * HD);
        kaf[c][1] = *(const short8_t*)(Kf + (size_t)(c * 32 + 16) * HD);
        vaf[c][0] = *(const short8_t*)(Vf0 + c * 32);
        vaf[c][1] = *(const short8_t*)(Vf1 + c * 32);
    }

    for (int it = 0; it < SEQ / 128; ++it) {
        const int kn = ((it + 1) * 128) & (SEQ - 1);   // wrap harmless
        const unsigned short* Kn = Kf + (size_t)kn * HD;

#pragma unroll
        for (int c = 0; c < 4; ++c) {
            floatx4 s0[2], s1[2];
            __builtin_amdgcn_s_setprio(1);
#pragma unroll
            for (int t = 0; t < 2; ++t) {
                s0[t] = __builtin_amdgcn_mfma_f32_16x16x32_bf16(kaf[c][0], qf[t], cinit, 0, 0, 0);
                s1[t] = __builtin_amdgcn_mfma_f32_16x16x32_bf16(kaf[c][1], qf[t], cinit, 0, 0, 0);
            }
            __builtin_amdgcn_s_setprio(0);
            // refill kaf[c] with next tile's fragments (last use was above)
            kaf[c][0] = *(const short8_t*)(Kn + (size_t)(c * 32) * HD);
            kaf[c][1] = *(const short8_t*)(Kn + (size_t)(c * 32 + 16) * HD);

            short8_t pb[2];
#pragma unroll
            for (int t = 0; t < 2; ++t) {
                const float p00 = EXP2F(s0[t][0]), p01 = EXP2F(s0[t][1]);
                const float p02 = EXP2F(s0[t][2]), p03 = EXP2F(s0[t][3]);
                const float p10 = EXP2F(s1[t][0]), p11 = EXP2F(s1[t][1]);
                const float p12 = EXP2F(s1[t][2]), p13 = EXP2F(s1[t][3]);
                const uint4 pu = {cvtpk(p00, p01), cvtpk(p02, p03),
                                  cvtpk(p10, p11), cvtpk(p12, p13)};
                pb[t] = __builtin_bit_cast(short8_t, pu);
            }
            __builtin_amdgcn_s_setprio(1);
#pragma unroll
            for (int t = 0; t < 2; ++t) {
                o[t][0] = __builtin_amdgcn_mfma_f32_16x16x32_bf16(vaf[c][0], pb[t], o[t][0], 0, 0, 0);
                o[t][1] = __builtin_amdgcn_mfma_f32_16x16x32_bf16(vaf[c][1], pb[t], o[t][1], 0, 0, 0);
                lacc[t] = __builtin_amdgcn_mfma_f32_16x16x32_bf16(ones, pb[t], lacc[t], 0, 0, 0);
            }
            __builtin_amdgcn_s_setprio(0);
            // refill vaf[c] with next tile's fragments (last use was above)
            vaf[c][0] = *(const short8_t*)(Vf0 + kn + c * 32);
            vaf[c][1] = *(const short8_t*)(Vf1 + kn + c * 32);
        }
    }

#pragma unroll
    for (int t = 0; t < 2; ++t) {
        const float inv = 1.f / lacc[t][0];   // full 2048-key sum, lane-local
        unsigned short* op = ab + (size_t)qrow[t] * CC + h * HD;
#pragma unroll
        for (int i = 0; i < 2; ++i) {
            uint2 u;
            u.x = pk_rn(o[t][i][0] * inv, o[t][i][1] * inv);
            u.y = pk_rn(o[t][i][2] * inv, o[t][i][3] * inv);
            *(uint2*)&op[i * 16 + quad * 4] = u;
        }
    }
}

// ---------------------------------------------------------------------------
// K3: out = att(bf16) @ W_proj + b_proj -> d_out fp32. A = direct b128
// loads, register-prefetched (no A-LDS). B dbuf staging.
// R23: 512 threads (8 waves: wm = m-half, wn = n-group), grid 256 = 1
// block/CU -> 2 waves/SIMD (was 1), W staged once per CU. (~neutral in R6,
// kept.)
// ---------------------------------------------------------------------------
__global__ __launch_bounds__(512) void proj_fast(
    const unsigned short* __restrict__ ab,   // bf16 att [B*S][C]
    const unsigned short* __restrict__ wT,   // WprojT bf16 [384][384]
    const float* __restrict__ bias,
    float* __restrict__ out)
{
    __shared__ __align__(16) unsigned short Bs[2][384][32];  // 49152 B

    const int mt   = blockIdx.x;
    const int tid  = threadIdx.x;
    const int wid  = tid >> 6;           // 0..7
    const int wn   = wid & 3;            // n-group (96 cols)
    const int wm   = wid >> 2;           // m-half (16 rows)
    const int lane = tid & 63;
    const int quad = lane >> 4;
    const int col  = lane & 15;
    const int m0   = mt * 32;

    floatx4 acc[6];
#pragma unroll
    for (int j = 0; j < 6; ++j) acc[j] = (floatx4){0.f, 0.f, 0.f, 0.f};

    const unsigned short* arow = ab + (size_t)(m0 + wm * 16 + col) * CC + quad * 8;

    const int f1 = tid;
    const int f2 = 512 + tid;
    const bool has2 = tid < 256;
    const unsigned short* wp1 = wT + (size_t)(f1 >> 1) * CC + (f1 & 1) * 16;
    const unsigned short* wp2 = wT + (size_t)(f2 >> 1) * CC + (f2 & 1) * 16;

    short8_t bA0, bA1, bB0, bB1;
    short8_t af;
    {
        bA0 = *(const short8_t*)wp1;
        bA1 = *(const short8_t*)(wp1 + 8);
        if (has2) {
            bB0 = *(const short8_t*)wp2;
            bB1 = *(const short8_t*)(wp2 + 8);
        }
        af = *(const short8_t*)arow;
        *(short8_t*)&Bs[0][f1 >> 1][(f1 & 1) * 16]     = bA0;
        *(short8_t*)&Bs[0][f1 >> 1][(f1 & 1) * 16 + 8] = bA1;
        if (has2) {
            *(short8_t*)&Bs[0][f2 >> 1][(f2 & 1) * 16]     = bB0;
            *(short8_t*)&Bs[0][f2 >> 1][(f2 & 1) * 16 + 8] = bB1;
        }
    }

    for (int it = 0; it < CC / 32; ++it) {
        const int kn = (it + 1 < CC / 32) ? (it + 1) * 32 : 0;
        bA0 = *(const short8_t*)(wp1 + kn);
        bA1 = *(const short8_t*)(wp1 + kn + 8);
        if (has2) {
            bB0 = *(const short8_t*)(wp2 + kn);
            bB1 = *(const short8_t*)(wp2 + kn + 8);
        }
        const short8_t afn = *(const short8_t*)(arow + kn);

        __syncthreads();
        const int p = it & 1;
        short8_t bf[6];
#pragma unroll
        for (int j = 0; j < 6; ++j)
            bf[j] = *(const short8_t*)&Bs[p][wn * 96 + j * 16 + col][quad * 8];
#pragma unroll
        for (int j = 0; j < 6; ++j)
            acc[j] = __builtin_amdgcn_mfma_f32_16x16x32_bf16(af, bf[j], acc[j], 0, 0, 0);

        *(short8_t*)&Bs[p ^ 1][f1 >> 1][(f1 & 1) * 16]     = bA0;
        *(short8_t*)&Bs[p ^ 1][f1 >> 1][(f1 & 1) * 16 + 8] = bA1;
        if (has2) {
            *(short8_t*)&Bs[p ^ 1][f2 >> 1][(f2 & 1) * 16]     = bB0;
            *(short8_t*)&Bs[p ^ 1][f2 >> 1][(f2 & 1) * 16 + 8] = bB1;
        }
        af = afn;
    }

#pragma unroll
    for (int j = 0; j < 6; ++j) {
        const int n = wn * 96 + j * 16 + col;
        const float bv = bias[n];
#pragma unroll
        for (int r = 0; r < 4; ++r)
            out[(size_t)(m0 + wm * 16 + quad * 4 + r) * CC + n] = acc[j][r] + bv;
    }
}

// ---------------------------------------------------------------------------
// Fallback kernels (R7/R18-compatible, only if ws lacks room for W^T + xb).
// fp32 Q/att in d_out; unscaled K; in-place proj. (Non-permuted V layout —
// written by qkv_lds, read by attn_f32; independent of the fast path.)
// ---------------------------------------------------------------------------
__global__ __launch_bounds__(256) void qkv_lds(
    const float* __restrict__ x, const float* __restrict__ w,
    float* __restrict__ dq, unsigned short* __restrict__ kv)
{
    __shared__ __align__(16) unsigned short wt[128 * 40];
    const int mt = blockIdx.x & 63, nb = blockIdx.x >> 6;
    const int tid = threadIdx.x, wid = tid >> 6, lane = tid & 63;
    const int quad = lane >> 4, col = lane & 15;
    const int wr = wid >> 1, wc = wid & 1;
    const int m0 = mt * 128, n0 = nb * 128;
    const int sn = tid >> 1, skg = (tid & 1) * 4;

    floatx4 acc[4][4];
#pragma unroll
    for (int i = 0; i < 4; ++i)
#pragma unroll
        for (int j = 0; j < 4; ++j) acc[i][j] = (floatx4){0.f, 0.f, 0.f, 0.f};
    const float* xbase = x + (size_t)(m0 + wr * 64 + col) * CC;

    for (int kb = 0; kb < CC; kb += 32) {
        float wv[4][4];
#pragma unroll
        for (int s = 0; s < 4; ++s) {
            const int k = kb + (skg + s) * 4;
#pragma unroll
            for (int j = 0; j < 4; ++j) wv[s][j] = w[(size_t)(k + j) * C3 + n0 + sn];
        }
        short8_t af[4];
#pragma unroll
        for (int i = 0; i < 4; ++i) {
            const float* xr = xbase + (size_t)i * 16 * CC + kb + quad * 8;
            af[i] = pack8(*(const float4*)xr, *(const float4*)(xr + 4));
        }
        __syncthreads();
#pragma unroll
        for (int s = 0; s < 4; ++s) {
            ushort4 u;
            u.x = f2bf(wv[s][0]); u.y = f2bf(wv[s][1]);
            u.z = f2bf(wv[s][2]); u.w = f2bf(wv[s][3]);
            *(ushort4*)&wt[sn * 40 + (skg + s) * 4] = u;
        }
        __syncthreads();
#pragma unroll
        for (int j = 0; j < 4; ++j) {
            const short8_t bf = *(const short8_t*)&wt[(wc * 64 + j * 16 + col) * 40 + quad * 8];
#pragma unroll
            for (int i = 0; i < 4; ++i)
                acc[i][j] = __builtin_amdgcn_mfma_f32_16x16x32_bf16(af[i], bf, acc[i][j], 0, 0, 0);
        }
    }
    const int t = nb / 3;
#pragma unroll
    for (int i = 0; i < 4; ++i) {
        const int mg = m0 + wr * 64 + i * 16 + quad * 4;
        if (t == 0) {
#pragma unroll
            for (int j = 0; j < 4; ++j) {
                const int n = n0 + wc * 64 + j * 16 + col;
#pragma unroll
                for (int r = 0; r < 4; ++r) dq[(size_t)(mg + r) * CC + n] = acc[i][j][r];
            }
        } else if (t == 1) {
            const int b = mg >> 11, s = mg & (SEQ - 1);
#pragma unroll
            for (int j = 0; j < 4; ++j) {
                const int rem = n0 - CC + wc * 64 + j * 16 + col;
                const int h = rem >> 5, d = rem & 31;
                unsigned short* kp = kv + ((size_t)(b * NH + h) * SEQ + s) * HD + d;
#pragma unroll
                for (int r = 0; r < 4; ++r) kp[(size_t)r * HD] = f2bf(acc[i][j][r]);
            }
        } else {
            const int b = mg >> 11, s = mg & (SEQ - 1);
            unsigned short* vtb = kv + (size_t)BB * NH * SEQ * HD;
#pragma unroll
            for (int j = 0; j < 4; ++j) {
                const int rem = n0 - 2 * CC + wc * 64 + j * 16 + col;
                const int h = rem >> 5, d = rem & 31;
                uint2 u;
                u.x = pk_rn(acc[i][j][0], acc[i][j][1]);
                u.y = pk_rn(acc[i][j][2], acc[i][j][3]);
                *(uint2*)&vtb[((size_t)(b * NH + h) * HD + d) * SEQ + s] = u;
            }
        }
    }
}

__global__ __launch_bounds__(256) void attn_f32(
    const unsigned short* __restrict__ kv,
    float* qatt)
{
    const int bid  = blockIdx.x;
    const int qp   = bid / 48;
    const int bh   = bid % 48;
    const int h    = bh % NH;
    const int b    = bh / NH;
    const int w    = threadIdx.x >> 6;
    const int lane = threadIdx.x & 63;
    const int quad = lane >> 4;
    const int col  = lane & 15;
    const int tid  = threadIdx.x;

    const unsigned short* K  = kv + (size_t)bh * SEQ * HD;
    const unsigned short* VT = kv + (size_t)BB * NH * SEQ * HD + (size_t)bh * HD * SEQ;

    __shared__ __align__(16) unsigned short Kt[2][128][40];
    __shared__ __align__(16) unsigned short Vt[2][32][136];

    const int krow_s = tid >> 1, koff_s = (tid & 1) * 16;
    const int drow_s = tid >> 3, voff_s = (tid & 7) * 16;

    int qrow[2];
    short8_t qf[2];
    const float sc = SCALE * LOG2E;
#pragma unroll
    for (int t = 0; t < 2; ++t) {
        qrow[t] = b * SEQ + qp * 128 + (w + 4 * t) * 16 + col;
        const float* qpt = qatt + (size_t)qrow[t] * CC + h * HD + quad * 8;
        const float4 a0 = *(const float4*)qpt;
        const float4 a1 = *(const float4*)(qpt + 4);
        const float4 s0 = {a0.x * sc, a0.y * sc, a0.z * sc, a0.w * sc};
        const float4 s1 = {a1.x * sc, a1.y * sc, a1.z * sc, a1.w * sc};
        qf[t] = pack8(s0, s1);
    }

    short8_t ones;
#pragma unroll
    for (int e = 0; e < 8; ++e) ones[e] = (short)0x3F80;

    floatx4 o[2][2];
    floatx4 lacc[2];
#pragma unroll
    for (int t = 0; t < 2; ++t) {
        lacc[t] = (floatx4){0.f, 0.f, 0.f, 0.f};
#pragma unroll
        for (int i = 0; i < 2; ++i) o[t][i] = (floatx4){0.f, 0.f, 0.f, 0.f};
    }
    const float ci = -10.f * LOG2E;
    const floatx4 cinit = {ci, ci, ci, ci};

    short8_t k0a = *(const short8_t*)(K + (size_t)krow_s * HD + koff_s);
    short8_t k0b = *(const short8_t*)(K + (size_t)krow_s * HD + koff_s + 8);
    short8_t v0a = *(const short8_t*)(VT + (size_t)drow_s * SEQ + voff_s);
    short8_t v0b = *(const short8_t*)(VT + (size_t)drow_s * SEQ + voff_s + 8);
    *(short8_t*)&Kt[0][krow_s][koff_s]     = k0a;
    *(short8_t*)&Kt[0][krow_s][koff_s + 8] = k0b;
    *(short8_t*)&Vt[0][drow_s][voff_s]     = v0a;
    *(short8_t*)&Vt[0][drow_s][voff_s + 8] = v0b;

    for (int it = 0; it < SEQ / 128; ++it) {
        const int kn = ((it + 1) * 128) & (SEQ - 1);
        k0a = *(const short8_t*)(K + (size_t)(kn + krow_s) * HD + koff_s);
        k0b = *(const short8_t*)(K + (size_t)(kn + krow_s) * HD + koff_s + 8);
        v0a = *(const short8_t*)(VT + (size_t)drow_s * SEQ + kn + voff_s);
        v0b = *(const short8_t*)(VT + (size_t)drow_s * SEQ + kn + voff_s + 8);

        __syncthreads();
        const int p = it & 1;

#pragma unroll
        for (int c = 0; c < 4; ++c) {
            const int c32 = c * 32;
            const short8_t ka0 = *(const short8_t*)&Kt[p][c32 + col][quad * 8];
            const short8_t ka1 = *(const short8_t*)&Kt[p][c32 + 16 + col][quad * 8];
            const uint2 w0a = *(const uint2*)&Vt[p][col][c32 + quad * 4];
            const uint2 w0b = *(const uint2*)&Vt[p][col][c32 + 16 + quad * 4];
            const uint2 w1a = *(const uint2*)&Vt[p][16 + col][c32 + quad * 4];
            const uint2 w1b = *(const uint2*)&Vt[p][16 + col][c32 + 16 + quad * 4];
            const short8_t va0 = __builtin_bit_cast(short8_t, (uint4){w0a.x, w0a.y, w0b.x, w0b.y});
            const short8_t va1 = __builtin_bit_cast(short8_t, (uint4){w1a.x, w1a.y, w1b.x, w1b.y});
#pragma unroll
            for (int t = 0; t < 2; ++t) {
                const floatx4 s0 = __builtin_amdgcn_mfma_f32_16x16x32_bf16(ka0, qf[t], cinit, 0, 0, 0);
                const floatx4 s1 = __builtin_amdgcn_mfma_f32_16x16x32_bf16(ka1, qf[t], cinit, 0, 0, 0);
                const float p00 = EXP2F(s0[0]), p01 = EXP2F(s0[1]);
                const float p02 = EXP2F(s0[2]), p03 = EXP2F(s0[3]);
                const float p10 = EXP2F(s1[0]), p11 = EXP2F(s1[1]);
                const float p12 = EXP2F(s1[2]), p13 = EXP2F(s1[3]);
                const uint4 pu = {pk_rn(p00, p01), pk_rn(p02, p03),
                                  pk_rn(p10, p11), pk_rn(p12, p13)};
                const short8_t pb = __builtin_bit_cast(short8_t, pu);
                o[t][0] = __builtin_amdgcn_mfma_f32_16x16x32_bf16(va0, pb, o[t][0], 0, 0, 0);
                o[t][1] = __builtin_amdgcn_mfma_f32_16x16x32_bf16(va1, pb, o[t][1], 0, 0, 0);
                lacc[t] = __builtin_amdgcn_mfma_f32_16x16x32_bf16(ones, pb, lacc[t], 0, 0, 0);
            }
        }

        *(short8_t*)&Kt[p ^ 1][krow_s][koff_s]     = k0a;
        *(short8_t*)&Kt[p ^ 1][krow_s][koff_s + 8] = k0b;
        *(short8_t*)&Vt[p ^ 1][drow_s][voff_s]     = v0a;
        *(short8_t*)&Vt[p ^ 1][drow_s][voff_s + 8] = v0b;
    }

#pragma unroll
    for (int t = 0; t < 2; ++t) {
        const float inv = 1.f / lacc[t][0];
        float* op = qatt + (size_t)qrow[t] * CC + h * HD;
#pragma unroll
        for (int r = 0; r < 4; ++r) {
            op[quad * 4 + r]      = o[t][0][r] * inv;
            op[16 + quad * 4 + r] = o[t][1][r] * inv;
        }
    }
}

__global__ __launch_bounds__(256) void proj_lds(
    float* att, const float* __restrict__ wp, const float* __restrict__ bias)
{
    __shared__ __align__(16) unsigned short wt[CC * 40];
    const int mt = blockIdx.x, tid = threadIdx.x, wid = tid >> 6, lane = tid & 63;
    const int quad = lane >> 4, col = lane & 15;
    const int m0 = mt * 16;
    floatx4 acc[6];
#pragma unroll
    for (int j = 0; j < 6; ++j) acc[j] = (floatx4){0.f, 0.f, 0.f, 0.f};
    for (int kb = 0; kb < CC; kb += 32) {
        float gv[12][4];
#pragma unroll
        for (int g = 0; g < 12; ++g) {
            const int flat = tid + g * 256, n = flat % 384, kg = flat / 384;
#pragma unroll
            for (int j = 0; j < 4; ++j) gv[g][j] = wp[(size_t)(kb + kg * 4 + j) * CC + n];
        }
        __syncthreads();
#pragma unroll
        for (int g = 0; g < 12; ++g) {
            const int flat = tid + g * 256, n = flat % 384, kg = flat / 384;
            ushort4 u;
            u.x = f2bf(gv[g][0]); u.y = f2bf(gv[g][1]);
            u.z = f2bf(gv[g][2]); u.w = f2bf(gv[g][3]);
            *(ushort4*)&wt[n * 40 + kg * 4] = u;
        }
        __syncthreads();
        const float* ap = att + (size_t)(m0 + col) * CC + kb + quad * 8;
        const short8_t af = pack8(*(const float4*)ap, *(const float4*)(ap + 4));
#pragma unroll
        for (int j = 0; j < 6; ++j) {
            const short8_t pb = *(const short8_t*)&wt[(wid * 96 + j * 16 + col) * 40 + quad * 8];
            acc[j] = __builtin_amdgcn_mfma_f32_16x16x32_bf16(af, pb, acc[j], 0, 0, 0);
        }
    }
    __syncthreads();
#pragma unroll
    for (int j = 0; j < 6; ++j) {
        const int n = wid * 96 + j * 16 + col;
        const float bv = bias[n];
#pragma unroll
        for (int r = 0; r < 4; ++r)
            att[(size_t)(m0 + quad * 4 + r) * CC + n] = acc[j][r] + bv;
    }
}

__global__ void marker_kernel(float* out, float val, int nelem) {
    int i = blockIdx.x * 256 + threadIdx.x;
    if (i < nelem) out[i] = val;
}

// ---------------------------------------------------------------------------
extern "C" void kernel_launch(void* const* d_in, const int* in_sizes, int n_in,
                              void* d_out, int out_size, void* d_ws, size_t ws_size,
                              hipStream_t stream)
{
    const float* x     = (const float*)d_in[0];
    const float* wqkv  = (const float*)d_in[1];
    const float* wproj = (const float*)d_in[2];
    const float* bproj = (const float*)d_in[3];
    float* out = (float*)d_out;
    unsigned short* kv = (unsigned short*)d_ws;

    if (ws_size < KV_BYTES) {
        const float marker = 100.f + (float)(ws_size >> 20);
        marker_kernel<<<(out_size + 255) / 256, 256, 0, stream>>>(out, marker, out_size);
        return;
    }

    unsigned short* wqkvT  = kv + (size_t)2 * BB * NH * SEQ * HD;
    unsigned short* wprojT = wqkvT + (size_t)C3 * CC;
    unsigned short* xb     = wprojT + (size_t)CC * CC;   // doubles as ab

    if (ws_size >= KV_BYTES + WT_BYTES + XB_BYTES) {
        unsigned short* qb = (unsigned short*)d_out;      // bf16 Q in d_out
        prep_kernel<<<144 + 1536, 256, 0, stream>>>(x, wqkv, wproj, wqkvT, wprojT, xb);
        qkv_fast<<<576, 256, 0, stream>>>(xb, wqkvT, qb, kv);
        attn_kernel<<<16 * BB * NH, 256, 0, stream>>>(kv, qb, xb /*ab: xb dead*/);
        proj_fast<<<BB * SEQ / 32, 512, 0, stream>>>(xb, wprojT, bproj, out);
    } else {
        qkv_lds<<<576, 256, 0, stream>>>(x, wqkv, out, kv);
        attn_f32<<<16 * BB * NH, 256, 0, stream>>>(kv, out);
        proj_lds<<<BB * SEQ / 16, 256, 0, stream>>>(out, wproj, bproj);
    }
}

// Round 8
// 132.888 us; speedup vs baseline: 1.2822x; 1.2822x over previous
//
#include <hip/hip_runtime.h>

// Problem constants
constexpr int BB  = 4;     // batch
constexpr int SEQ = 2048;  // sequence length
constexpr int CC  = 384;   // model dim
constexpr int C3  = 1152;  // 3*C
constexpr int NH  = 12;    // heads
constexpr int HD  = 32;    // head dim
constexpr float SCALE = 0.17677669529663689f;  // 32^-0.5
constexpr float LOG2E = 1.4426950408889634f;
constexpr float KSC   = SCALE * LOG2E;         // folded into K at qkv epilogue
constexpr size_t KV_BYTES = (size_t)2 * BB * NH * SEQ * HD * 2;
constexpr size_t WT_BYTES = ((size_t)C3 * CC + (size_t)CC * CC) * 2;
constexpr size_t XB_BYTES = (size_t)BB * SEQ * CC * 2;

typedef __attribute__((ext_vector_type(8))) short short8_t;    // 8 bf16 (16 B)
typedef __attribute__((ext_vector_type(4))) float floatx4;     // MFMA C/D

#if __has_builtin(__builtin_amdgcn_exp2f)
#define EXP2F __builtin_amdgcn_exp2f
#else
#define EXP2F __builtin_exp2f
#endif

__device__ __forceinline__ unsigned short f2bf(float f) {
    unsigned int u = __builtin_bit_cast(unsigned int, f);
    u += 0x7fffu + ((u >> 16) & 1u);   // RNE
    return (unsigned short)(u >> 16);
}
// Round-nearest bf16 pair pack: 2 adds + 1 perm, all full-rate.
__device__ __forceinline__ unsigned int pk_rn(float lo, float hi) {
    return __builtin_amdgcn_perm(__builtin_bit_cast(unsigned int, hi) + 0x8000u,
                                 __builtin_bit_cast(unsigned int, lo) + 0x8000u,
                                 0x07060302u);
}
// Single-op RNE bf16 pair pack for the attn hot loop (gfx950 VOP3).
__device__ __forceinline__ unsigned int cvtpk(float lo, float hi) {
    unsigned int r;
    asm("v_cvt_pk_bf16_f32 %0, %1, %2" : "=v"(r) : "v"(lo), "v"(hi));
    return r;
}
__device__ __forceinline__ short8_t pack8(float4 a, float4 b) {
    uint4 u;
    u.x = pk_rn(a.x, a.y); u.y = pk_rn(a.z, a.w);
    u.z = pk_rn(b.x, b.y); u.w = pk_rn(b.z, b.w);
    return __builtin_bit_cast(short8_t, u);
}

// Permuted V-tile store: source = 16 consecutive keys of one d-row (2 b128
// global loads); dest = MFMA-fragment order within the 32-key chunk so the
// PV A-operand is a single b128 read. Chunk layout: key q*4+j -> pos q*8+j,
// key 16+q*4+j -> pos q*8+4+j. 4x ds_write_b64.
__device__ __forceinline__ void vstore(unsigned short* vb, short8_t a, short8_t b) {
    const uint4 ua = __builtin_bit_cast(uint4, a);
    const uint4 ub = __builtin_bit_cast(uint4, b);
    *(uint2*)(vb)      = (uint2){ua.x, ua.y};
    *(uint2*)(vb + 8)  = (uint2){ua.z, ua.w};
    *(uint2*)(vb + 16) = (uint2){ub.x, ub.y};
    *(uint2*)(vb + 24) = (uint2){ub.z, ub.w};
}

// ---------------------------------------------------------------------------
// K0: prep. bid<144: transpose W_qkv/W_proj to bf16 [n][k] (stride CC).
// bid>=144: convert x to bf16 row-major.
// ---------------------------------------------------------------------------
__global__ __launch_bounds__(256) void prep_kernel(
    const float* __restrict__ x, const float* __restrict__ wqkv,
    const float* __restrict__ wproj,
    unsigned short* __restrict__ wqkvT, unsigned short* __restrict__ wprojT,
    unsigned short* __restrict__ xb)
{
    const int bid = blockIdx.x;
    if (bid >= 144) {                  // x -> bf16, 2048 elems per block
        const size_t base = (size_t)(bid - 144) * 2048 + threadIdx.x * 8;
        const float4 a = *(const float4*)(x + base);
        const float4 b = *(const float4*)(x + base + 4);
        uint4 u;
        u.x = pk_rn(a.x, a.y); u.y = pk_rn(a.z, a.w);
        u.z = pk_rn(b.x, b.y); u.w = pk_rn(b.z, b.w);
        *(uint4*)(xb + base) = u;
        return;
    }
    __shared__ float ls[64][68];
    const float* src; unsigned short* dst; int SN, k0, n0;
    if (bid < 108) {                   // Wqkv: 6 k-tiles x 18 n-tiles
        src = wqkv; dst = wqkvT; SN = C3;
        k0 = (bid / 18) * 64; n0 = (bid % 18) * 64;
    } else {                           // Wproj: 6 x 6
        const int b2 = bid - 108;
        src = wproj; dst = wprojT; SN = CC;
        k0 = (b2 / 6) * 64; n0 = (b2 % 6) * 64;
    }
    const int t  = threadIdx.x;
    const int rr = t >> 4, cc4 = (t & 15) * 4;
#pragma unroll
    for (int p = 0; p < 4; ++p) {
        const int row = p * 16 + rr;
        const float4 v = *(const float4*)&src[(size_t)(k0 + row) * SN + n0 + cc4];
        ls[row][cc4] = v.x; ls[row][cc4 + 1] = v.y;
        ls[row][cc4 + 2] = v.z; ls[row][cc4 + 3] = v.w;
    }
    __syncthreads();
#pragma unroll
    for (int p = 0; p < 4; ++p) {
        const int nrow = p * 16 + rr;
        uint2 u;
        u.x = pk_rn(ls[cc4][nrow],     ls[cc4 + 1][nrow]);
        u.y = pk_rn(ls[cc4 + 2][nrow], ls[cc4 + 3][nrow]);
        *(uint2*)&dst[(size_t)(n0 + nrow) * CC + k0 + cc4] = u;
    }
}

// ---------------------------------------------------------------------------
// K1: qkv = x @ W_qkv. R18-passing structure (128m x 128n, grid 576, dbuf
// LDS staging, direct b128 A loads from xb). R19 epilogue: Q written BF16 to
// qb; K pre-scaled by SCALE*LOG2E. R25: V epilogue reverted to natural
// layout (R24's global permutation caused L1 thrash in attn; the LDS vstore
// re-permutes instead).
// ---------------------------------------------------------------------------
__global__ __launch_bounds__(256) void qkv_fast(
    const unsigned short* __restrict__ xb,
    const unsigned short* __restrict__ wT,   // WqkvT bf16 [1152][384]
    unsigned short* __restrict__ qb,         // d_out as bf16 [B*S][C]
    unsigned short* __restrict__ kv)
{
    __shared__ __align__(16) unsigned short As[2][128][40];  // 20480 B
    __shared__ __align__(16) unsigned short Bs[2][128][40];  // 20480 B

    const int mt   = blockIdx.x & 63;
    const int nb   = blockIdx.x >> 6;
    const int tid  = threadIdx.x;
    const int wid  = tid >> 6;
    const int lane = tid & 63;
    const int quad = lane >> 4;
    const int col  = lane & 15;
    const int wr   = wid >> 1, wc = wid & 1;
    const int m0 = mt * 128, n0 = nb * 128;

    const int arow = tid >> 1;
    const int aoff = (tid & 1) * 16;

    floatx4 acc[4][4];
#pragma unroll
    for (int i = 0; i < 4; ++i)
#pragma unroll
        for (int j = 0; j < 4; ++j) acc[i][j] = (floatx4){0.f, 0.f, 0.f, 0.f};

    const unsigned short* xrow = xb + (size_t)(m0 + arow) * CC + aoff;
    const unsigned short* wrow = wT + (size_t)(n0 + arow) * CC + aoff;

    short8_t ast0, ast1, bst0, bst1;
    ast0 = *(const short8_t*)xrow;
    ast1 = *(const short8_t*)(xrow + 8);
    bst0 = *(const short8_t*)wrow;
    bst1 = *(const short8_t*)(wrow + 8);
    *(short8_t*)&As[0][arow][aoff]     = ast0;
    *(short8_t*)&As[0][arow][aoff + 8] = ast1;
    *(short8_t*)&Bs[0][arow][aoff]     = bst0;
    *(short8_t*)&Bs[0][arow][aoff + 8] = bst1;

    for (int it = 0; it < CC / 32; ++it) {
        const int kn = (it + 1 < CC / 32) ? (it + 1) * 32 : 0;  // wrap harmless
        ast0 = *(const short8_t*)(xrow + kn);
        ast1 = *(const short8_t*)(xrow + kn + 8);
        bst0 = *(const short8_t*)(wrow + kn);
        bst1 = *(const short8_t*)(wrow + kn + 8);

        __syncthreads();
        const int p = it & 1;
        short8_t af[4], bf[4];
#pragma unroll
        for (int i = 0; i < 4; ++i)
            af[i] = *(const short8_t*)&As[p][wr * 64 + i * 16 + col][quad * 8];
#pragma unroll
        for (int j = 0; j < 4; ++j)
            bf[j] = *(const short8_t*)&Bs[p][wc * 64 + j * 16 + col][quad * 8];
#pragma unroll
        for (int j = 0; j < 4; ++j)
#pragma unroll
            for (int i = 0; i < 4; ++i)
                acc[i][j] = __builtin_amdgcn_mfma_f32_16x16x32_bf16(af[i], bf[j], acc[i][j], 0, 0, 0);

        *(short8_t*)&As[p ^ 1][arow][aoff]     = ast0;
        *(short8_t*)&As[p ^ 1][arow][aoff + 8] = ast1;
        *(short8_t*)&Bs[p ^ 1][arow][aoff]     = bst0;
        *(short8_t*)&Bs[p ^ 1][arow][aoff + 8] = bst1;
    }

    const int t = nb / 3;              // 0:q 1:k 2:v (uniform per block)
#pragma unroll
    for (int i = 0; i < 4; ++i) {
        const int mg = m0 + wr * 64 + i * 16 + quad * 4;
        if (t == 0) {
#pragma unroll
            for (int j = 0; j < 4; ++j) {
                const int n = n0 + wc * 64 + j * 16 + col;
#pragma unroll
                for (int r = 0; r < 4; ++r)
                    qb[(size_t)(mg + r) * CC + n] = f2bf(acc[i][j][r]);
            }
        } else if (t == 1) {
            const int b = mg >> 11, s = mg & (SEQ - 1);
#pragma unroll
            for (int j = 0; j < 4; ++j) {
                const int rem = n0 - CC + wc * 64 + j * 16 + col;
                const int h = rem >> 5, d = rem & 31;
                unsigned short* kp = kv + ((size_t)(b * NH + h) * SEQ + s) * HD + d;
#pragma unroll
                for (int r = 0; r < 4; ++r)
                    kp[(size_t)r * HD] = f2bf(acc[i][j][r] * KSC);  // pre-scaled
            }
        } else {
            const int b = mg >> 11, s = mg & (SEQ - 1);
            unsigned short* vtb = kv + (size_t)BB * NH * SEQ * HD;
#pragma unroll
            for (int j = 0; j < 4; ++j) {
                const int rem = n0 - 2 * CC + wc * 64 + j * 16 + col;
                const int h = rem >> 5, d = rem & 31;
                uint2 u;
                u.x = pk_rn(acc[i][j][0], acc[i][j][1]);
                u.y = pk_rn(acc[i][j][2], acc[i][j][3]);
                *(uint2*)&vtb[((size_t)(b * NH + h) * HD + d) * SEQ + s] = u;
            }
        }
    }
}

// ---------------------------------------------------------------------------
// K2: MFMA flash attention — R25: revert to best-measured R22 structure
// (128 q-rows, V->LDS permuted vstore, K register-direct; R24's zero-LDS
// thrashed L1: 3 blocks x 16KB/tile > 32KB -> V frags from L2, attn 77us).
// NEW in R25: chunk-skewed pipeline — QK(c+1) MFMAs issue BEFORE exp(c),
// so matrix pipe (next scores) overlaps VALU (current exp/pack). Source-
// order-only change; +16 VGPR (n0/n1); no new sync.
// ---------------------------------------------------------------------------
__global__ __launch_bounds__(256, 3) void attn_kernel(
    const unsigned short* __restrict__ kv,
    const unsigned short* __restrict__ qb,   // bf16 Q [B*S][C] (d_out)
    unsigned short* __restrict__ ab)         // bf16 att [B*S][C] (= xb space)
{
    const int bid  = blockIdx.x;
    const int qp   = bid / 48;
    const int bh   = bid % 48;
    const int h    = bh % NH;
    const int b    = bh / NH;
    const int w    = threadIdx.x >> 6;
    const int lane = threadIdx.x & 63;
    const int quad = lane >> 4;
    const int col  = lane & 15;
    const int tid  = threadIdx.x;

    const unsigned short* K  = kv + (size_t)bh * SEQ * HD;
    const unsigned short* VT = kv + (size_t)BB * NH * SEQ * HD + (size_t)bh * HD * SEQ;

    __shared__ __align__(16) unsigned short Vt[2][32][136];  // 17408 B (permuted keys)

    const int drow_s = tid >> 3, voff_s = (tid & 7) * 16;
    const int vbase  = ((tid & 6) >> 1) * 32 + (tid & 1) * 4;  // chunk*32 + half*4

    // per-thread K fragment base: row = col, elems quad*8..+7
    const unsigned short* Kf = K + (size_t)col * HD + quad * 8;

    int qrow[2];
    short8_t qf[2];
#pragma unroll
    for (int t = 0; t < 2; ++t) {
        qrow[t] = b * SEQ + qp * 128 + (w + 4 * t) * 16 + col;
        qf[t] = *(const short8_t*)(qb + (size_t)qrow[t] * CC + h * HD + quad * 8);
    }

    short8_t ones;
#pragma unroll
    for (int e = 0; e < 8; ++e) ones[e] = (short)0x3F80;

    floatx4 o[2][2];
    floatx4 lacc[2];
#pragma unroll
    for (int t = 0; t < 2; ++t) {
        lacc[t] = (floatx4){0.f, 0.f, 0.f, 0.f};
#pragma unroll
        for (int i = 0; i < 2; ++i) o[t][i] = (floatx4){0.f, 0.f, 0.f, 0.f};
    }
    const float ci = -10.f * LOG2E;
    const floatx4 cinit = {ci, ci, ci, ci};

    // prologue: V tile 0 -> LDS buf 0; K tile 0 fragments -> registers
    short8_t v0a = *(const short8_t*)(VT + (size_t)drow_s * SEQ + voff_s);
    short8_t v0b = *(const short8_t*)(VT + (size_t)drow_s * SEQ + voff_s + 8);
    vstore(&Vt[0][drow_s][vbase], v0a, v0b);

    short8_t kaf[4][2];
#pragma unroll
    for (int c = 0; c < 4; ++c) {
        kaf[c][0] = *(const short8_t*)(Kf + (size_t)(c * 32) * HD);
        kaf[c][1] = *(const short8_t*)(Kf + (size_t)(c * 32 + 16) * HD);
    }

    for (int it = 0; it < SEQ / 128; ++it) {
        const int kn = ((it + 1) * 128) & (SEQ - 1);
        v0a = *(const short8_t*)(VT + (size_t)drow_s * SEQ + kn + voff_s);
        v0b = *(const short8_t*)(VT + (size_t)drow_s * SEQ + kn + voff_s + 8);
        const unsigned short* Kn = Kf + (size_t)kn * HD;

        __syncthreads();
        const int p = it & 1;

        // hoist V fragment reads for this tile
        short8_t va[4][2];
#pragma unroll
        for (int c = 0; c < 4; ++c) {
            const int c32 = c * 32;
            va[c][0] = *(const short8_t*)&Vt[p][col][c32 + quad * 8];
            va[c][1] = *(const short8_t*)&Vt[p][16 + col][c32 + quad * 8];
        }

        // skew prologue: QK for chunk 0
        floatx4 s0[2], s1[2];
        __builtin_amdgcn_s_setprio(1);
#pragma unroll
        for (int t = 0; t < 2; ++t) {
            s0[t] = __builtin_amdgcn_mfma_f32_16x16x32_bf16(kaf[0][0], qf[t], cinit, 0, 0, 0);
            s1[t] = __builtin_amdgcn_mfma_f32_16x16x32_bf16(kaf[0][1], qf[t], cinit, 0, 0, 0);
        }
        __builtin_amdgcn_s_setprio(0);
        kaf[0][0] = *(const short8_t*)(Kn);
        kaf[0][1] = *(const short8_t*)(Kn + (size_t)16 * HD);

#pragma unroll
        for (int c = 0; c < 4; ++c) {
            floatx4 n0[2], n1[2];
            if (c < 3) {
                // QK(c+1) issued BEFORE exp(c): matrix pipe overlaps VALU
                __builtin_amdgcn_s_setprio(1);
#pragma unroll
                for (int t = 0; t < 2; ++t) {
                    n0[t] = __builtin_amdgcn_mfma_f32_16x16x32_bf16(kaf[c + 1][0], qf[t], cinit, 0, 0, 0);
                    n1[t] = __builtin_amdgcn_mfma_f32_16x16x32_bf16(kaf[c + 1][1], qf[t], cinit, 0, 0, 0);
                }
                __builtin_amdgcn_s_setprio(0);
                kaf[c + 1][0] = *(const short8_t*)(Kn + (size_t)((c + 1) * 32) * HD);
                kaf[c + 1][1] = *(const short8_t*)(Kn + (size_t)((c + 1) * 32 + 16) * HD);
            }

            short8_t pb[2];
#pragma unroll
            for (int t = 0; t < 2; ++t) {
                const float p00 = EXP2F(s0[t][0]), p01 = EXP2F(s0[t][1]);
                const float p02 = EXP2F(s0[t][2]), p03 = EXP2F(s0[t][3]);
                const float p10 = EXP2F(s1[t][0]), p11 = EXP2F(s1[t][1]);
                const float p12 = EXP2F(s1[t][2]), p13 = EXP2F(s1[t][3]);
                const uint4 pu = {cvtpk(p00, p01), cvtpk(p02, p03),
                                  cvtpk(p10, p11), cvtpk(p12, p13)};
                pb[t] = __builtin_bit_cast(short8_t, pu);
            }
            __builtin_amdgcn_s_setprio(1);
#pragma unroll
            for (int t = 0; t < 2; ++t) {
                o[t][0] = __builtin_amdgcn_mfma_f32_16x16x32_bf16(va[c][0], pb[t], o[t][0], 0, 0, 0);
                o[t][1] = __builtin_amdgcn_mfma_f32_16x16x32_bf16(va[c][1], pb[t], o[t][1], 0, 0, 0);
                lacc[t] = __builtin_amdgcn_mfma_f32_16x16x32_bf16(ones, pb[t], lacc[t], 0, 0, 0);
            }
            __builtin_amdgcn_s_setprio(0);
            if (c < 3) {
#pragma unroll
                for (int t = 0; t < 2; ++t) { s0[t] = n0[t]; s1[t] = n1[t]; }
            }
        }

        vstore(&Vt[p ^ 1][drow_s][vbase], v0a, v0b);
    }

#pragma unroll
    for (int t = 0; t < 2; ++t) {
        const float inv = 1.f / lacc[t][0];   // full 2048-key sum, lane-local
        unsigned short* op = ab + (size_t)qrow[t] * CC + h * HD;
#pragma unroll
        for (int i = 0; i < 2; ++i) {
            uint2 u;
            u.x = pk_rn(o[t][i][0] * inv, o[t][i][1] * inv);
            u.y = pk_rn(o[t][i][2] * inv, o[t][i][3] * inv);
            *(uint2*)&op[i * 16 + quad * 4] = u;
        }
    }
}

// ---------------------------------------------------------------------------
// K3: out = att(bf16) @ W_proj + b_proj -> d_out fp32. A = direct b128
// loads, register-prefetched (no A-LDS). B dbuf staging.
// R23: 512 threads (8 waves: wm = m-half, wn = n-group), grid 256 = 1
// block/CU -> 2 waves/SIMD, W staged once per CU. (neutral in R6, kept.)
// ---------------------------------------------------------------------------
__global__ __launch_bounds__(512) void proj_fast(
    const unsigned short* __restrict__ ab,   // bf16 att [B*S][C]
    const unsigned short* __restrict__ wT,   // WprojT bf16 [384][384]
    const float* __restrict__ bias,
    float* __restrict__ out)
{
    __shared__ __align__(16) unsigned short Bs[2][384][32];  // 49152 B

    const int mt   = blockIdx.x;
    const int tid  = threadIdx.x;
    const int wid  = tid >> 6;           // 0..7
    const int wn   = wid & 3;            // n-group (96 cols)
    const int wm   = wid >> 2;           // m-half (16 rows)
    const int lane = tid & 63;
    const int quad = lane >> 4;
    const int col  = lane & 15;
    const int m0   = mt * 32;

    floatx4 acc[6];
#pragma unroll
    for (int j = 0; j < 6; ++j) acc[j] = (floatx4){0.f, 0.f, 0.f, 0.f};

    const unsigned short* arow = ab + (size_t)(m0 + wm * 16 + col) * CC + quad * 8;

    const int f1 = tid;
    const int f2 = 512 + tid;
    const bool has2 = tid < 256;
    const unsigned short* wp1 = wT + (size_t)(f1 >> 1) * CC + (f1 & 1) * 16;
    const unsigned short* wp2 = wT + (size_t)(f2 >> 1) * CC + (f2 & 1) * 16;

    short8_t bA0, bA1, bB0, bB1;
    short8_t af;
    {
        bA0 = *(const short8_t*)wp1;
        bA1 = *(const short8_t*)(wp1 + 8);
        if (has2) {
            bB0 = *(const short8_t*)wp2;
            bB1 = *(const short8_t*)(wp2 + 8);
        }
        af = *(const short8_t*)arow;
        *(short8_t*)&Bs[0][f1 >> 1][(f1 & 1) * 16]     = bA0;
        *(short8_t*)&Bs[0][f1 >> 1][(f1 & 1) * 16 + 8] = bA1;
        if (has2) {
            *(short8_t*)&Bs[0][f2 >> 1][(f2 & 1) * 16]     = bB0;
            *(short8_t*)&Bs[0][f2 >> 1][(f2 & 1) * 16 + 8] = bB1;
        }
    }

    for (int it = 0; it < CC / 32; ++it) {
        const int kn = (it + 1 < CC / 32) ? (it + 1) * 32 : 0;
        bA0 = *(const short8_t*)(wp1 + kn);
        bA1 = *(const short8_t*)(wp1 + kn + 8);
        if (has2) {
            bB0 = *(const short8_t*)(wp2 + kn);
            bB1 = *(const short8_t*)(wp2 + kn + 8);
        }
        const short8_t afn = *(const short8_t*)(arow + kn);

        __syncthreads();
        const int p = it & 1;
        short8_t bf[6];
#pragma unroll
        for (int j = 0; j < 6; ++j)
            bf[j] = *(const short8_t*)&Bs[p][wn * 96 + j * 16 + col][quad * 8];
#pragma unroll
        for (int j = 0; j < 6; ++j)
            acc[j] = __builtin_amdgcn_mfma_f32_16x16x32_bf16(af, bf[j], acc[j], 0, 0, 0);

        *(short8_t*)&Bs[p ^ 1][f1 >> 1][(f1 & 1) * 16]     = bA0;
        *(short8_t*)&Bs[p ^ 1][f1 >> 1][(f1 & 1) * 16 + 8] = bA1;
        if (has2) {
            *(short8_t*)&Bs[p ^ 1][f2 >> 1][(f2 & 1) * 16]     = bB0;
            *(short8_t*)&Bs[p ^ 1][f2 >> 1][(f2 & 1) * 16 + 8] = bB1;
        }
        af = afn;
    }

#pragma unroll
    for (int j = 0; j < 6; ++j) {
        const int n = wn * 96 + j * 16 + col;
        const float bv = bias[n];
#pragma unroll
        for (int r = 0; r < 4; ++r)
            out[(size_t)(m0 + wm * 16 + quad * 4 + r) * CC + n] = acc[j][r] + bv;
    }
}

// ---------------------------------------------------------------------------
// Fallback kernels (R7/R18-compatible, only if ws lacks room for W^T + xb).
// fp32 Q/att in d_out; unscaled K; in-place proj.
// ---------------------------------------------------------------------------
__global__ __launch_bounds__(256) void qkv_lds(
    const float* __restrict__ x, const float* __restrict__ w,
    float* __restrict__ dq, unsigned short* __restrict__ kv)
{
    __shared__ __align__(16) unsigned short wt[128 * 40];
    const int mt = blockIdx.x & 63, nb = blockIdx.x >> 6;
    const int tid = threadIdx.x, wid = tid >> 6, lane = tid & 63;
    const int quad = lane >> 4, col = lane & 15;
    const int wr = wid >> 1, wc = wid & 1;
    const int m0 = mt * 128, n0 = nb * 128;
    const int sn = tid >> 1, skg = (tid & 1) * 4;

    floatx4 acc[4][4];
#pragma unroll
    for (int i = 0; i < 4; ++i)
#pragma unroll
        for (int j = 0; j < 4; ++j) acc[i][j] = (floatx4){0.f, 0.f, 0.f, 0.f};
    const float* xbase = x + (size_t)(m0 + wr * 64 + col) * CC;

    for (int kb = 0; kb < CC; kb += 32) {
        float wv[4][4];
#pragma unroll
        for (int s = 0; s < 4; ++s) {
            const int k = kb + (skg + s) * 4;
#pragma unroll
            for (int j = 0; j < 4; ++j) wv[s][j] = w[(size_t)(k + j) * C3 + n0 + sn];
        }
        short8_t af[4];
#pragma unroll
        for (int i = 0; i < 4; ++i) {
            const float* xr = xbase + (size_t)i * 16 * CC + kb + quad * 8;
            af[i] = pack8(*(const float4*)xr, *(const float4*)(xr + 4));
        }
        __syncthreads();
#pragma unroll
        for (int s = 0; s < 4; ++s) {
            ushort4 u;
            u.x = f2bf(wv[s][0]); u.y = f2bf(wv[s][1]);
            u.z = f2bf(wv[s][2]); u.w = f2bf(wv[s][3]);
            *(ushort4*)&wt[sn * 40 + (skg + s) * 4] = u;
        }
        __syncthreads();
#pragma unroll
        for (int j = 0; j < 4; ++j) {
            const short8_t bf = *(const short8_t*)&wt[(wc * 64 + j * 16 + col) * 40 + quad * 8];
#pragma unroll
            for (int i = 0; i < 4; ++i)
                acc[i][j] = __builtin_amdgcn_mfma_f32_16x16x32_bf16(af[i], bf, acc[i][j], 0, 0, 0);
        }
    }
    const int t = nb / 3;
#pragma unroll
    for (int i = 0; i < 4; ++i) {
        const int mg = m0 + wr * 64 + i * 16 + quad * 4;
        if (t == 0) {
#pragma unroll
            for (int j = 0; j < 4; ++j) {
                const int n = n0 + wc * 64 + j * 16 + col;
#pragma unroll
                for (int r = 0; r < 4; ++r) dq[(size_t)(mg + r) * CC + n] = acc[i][j][r];
            }
        } else if (t == 1) {
            const int b = mg >> 11, s = mg & (SEQ - 1);
#pragma unroll
            for (int j = 0; j < 4; ++j) {
                const int rem = n0 - CC + wc * 64 + j * 16 + col;
                const int h = rem >> 5, d = rem & 31;
                unsigned short* kp = kv + ((size_t)(b * NH + h) * SEQ + s) * HD + d;
#pragma unroll
                for (int r = 0; r < 4; ++r) kp[(size_t)r * HD] = f2bf(acc[i][j][r]);
            }
        } else {
            const int b = mg >> 11, s = mg & (SEQ - 1);
            unsigned short* vtb = kv + (size_t)BB * NH * SEQ * HD;
#pragma unroll
            for (int j = 0; j < 4; ++j) {
                const int rem = n0 - 2 * CC + wc * 64 + j * 16 + col;
                const int h = rem >> 5, d = rem & 31;
                uint2 u;
                u.x = pk_rn(acc[i][j][0], acc[i][j][1]);
                u.y = pk_rn(acc[i][j][2], acc[i][j][3]);
                *(uint2*)&vtb[((size_t)(b * NH + h) * HD + d) * SEQ + s] = u;
            }
        }
    }
}

__global__ __launch_bounds__(256) void attn_f32(
    const unsigned short* __restrict__ kv,
    float* qatt)
{
    const int bid  = blockIdx.x;
    const int qp   = bid / 48;
    const int bh   = bid % 48;
    const int h    = bh % NH;
    const int b    = bh / NH;
    const int w    = threadIdx.x >> 6;
    const int lane = threadIdx.x & 63;
    const int quad = lane >> 4;
    const int col  = lane & 15;
    const int tid  = threadIdx.x;

    const unsigned short* K  = kv + (size_t)bh * SEQ * HD;
    const unsigned short* VT = kv + (size_t)BB * NH * SEQ * HD + (size_t)bh * HD * SEQ;

    __shared__ __align__(16) unsigned short Kt[2][128][40];
    __shared__ __align__(16) unsigned short Vt[2][32][136];

    const int krow_s = tid >> 1, koff_s = (tid & 1) * 16;
    const int drow_s = tid >> 3, voff_s = (tid & 7) * 16;

    int qrow[2];
    short8_t qf[2];
    const float sc = SCALE * LOG2E;
#pragma unroll
    for (int t = 0; t < 2; ++t) {
        qrow[t] = b * SEQ + qp * 128 + (w + 4 * t) * 16 + col;
        const float* qpt = qatt + (size_t)qrow[t] * CC + h * HD + quad * 8;
        const float4 a0 = *(const float4*)qpt;
        const float4 a1 = *(const float4*)(qpt + 4);
        const float4 s0 = {a0.x * sc, a0.y * sc, a0.z * sc, a0.w * sc};
        const float4 s1 = {a1.x * sc, a1.y * sc, a1.z * sc, a1.w * sc};
        qf[t] = pack8(s0, s1);
    }

    short8_t ones;
#pragma unroll
    for (int e = 0; e < 8; ++e) ones[e] = (short)0x3F80;

    floatx4 o[2][2];
    floatx4 lacc[2];
#pragma unroll
    for (int t = 0; t < 2; ++t) {
        lacc[t] = (floatx4){0.f, 0.f, 0.f, 0.f};
#pragma unroll
        for (int i = 0; i < 2; ++i) o[t][i] = (floatx4){0.f, 0.f, 0.f, 0.f};
    }
    const float ci = -10.f * LOG2E;
    const floatx4 cinit = {ci, ci, ci, ci};

    short8_t k0a = *(const short8_t*)(K + (size_t)krow_s * HD + koff_s);
    short8_t k0b = *(const short8_t*)(K + (size_t)krow_s * HD + koff_s + 8);
    short8_t v0a = *(const short8_t*)(VT + (size_t)drow_s * SEQ + voff_s);
    short8_t v0b = *(const short8_t*)(VT + (size_t)drow_s * SEQ + voff_s + 8);
    *(short8_t*)&Kt[0][krow_s][koff_s]     = k0a;
    *(short8_t*)&Kt[0][krow_s][koff_s + 8] = k0b;
    *(short8_t*)&Vt[0][drow_s][voff_s]     = v0a;
    *(short8_t*)&Vt[0][drow_s][voff_s + 8] = v0b;

    for (int it = 0; it < SEQ / 128; ++it) {
        const int kn = ((it + 1) * 128) & (SEQ - 1);
        k0a = *(const short8_t*)(K + (size_t)(kn + krow_s) * HD + koff_s);
        k0b = *(const short8_t*)(K + (size_t)(kn + krow_s) * HD + koff_s + 8);
        v0a = *(const short8_t*)(VT + (size_t)drow_s * SEQ + kn + voff_s);
        v0b = *(const short8_t*)(VT + (size_t)drow_s * SEQ + kn + voff_s + 8);

        __syncthreads();
        const int p = it & 1;

#pragma unroll
        for (int c = 0; c < 4; ++c) {
            const int c32 = c * 32;
            const short8_t ka0 = *(const short8_t*)&Kt[p][c32 + col][quad * 8];
            const short8_t ka1 = *(const short8_t*)&Kt[p][c32 + 16 + col][quad * 8];
            const uint2 w0a = *(const uint2*)&Vt[p][col][c32 + quad * 4];
            const uint2 w0b = *(const uint2*)&Vt[p][col][c32 + 16 + quad * 4];
            const uint2 w1a = *(const uint2*)&Vt[p][16 + col][c32 + quad * 4];
            const uint2 w1b = *(const uint2*)&Vt[p][16 + col][c32 + 16 + quad * 4];
            const short8_t va0 = __builtin_bit_cast(short8_t, (uint4){w0a.x, w0a.y, w0b.x, w0b.y});
            const short8_t va1 = __builtin_bit_cast(short8_t, (uint4){w1a.x, w1a.y, w1b.x, w1b.y});
#pragma unroll
            for (int t = 0; t < 2; ++t) {
                const floatx4 s0 = __builtin_amdgcn_mfma_f32_16x16x32_bf16(ka0, qf[t], cinit, 0, 0, 0);
                const floatx4 s1 = __builtin_amdgcn_mfma_f32_16x16x32_bf16(ka1, qf[t], cinit, 0, 0, 0);
                const float p00 = EXP2F(s0[0]), p01 = EXP2F(s0[1]);
                const float p02 = EXP2F(s0[2]), p03 = EXP2F(s0[3]);
                const float p10 = EXP2F(s1[0]), p11 = EXP2F(s1[1]);
                const float p12 = EXP2F(s1[2]), p13 = EXP2F(s1[3]);
                const uint4 pu = {pk_rn(p00, p01), pk_rn(p02, p03),
                                  pk_rn(p10, p11), pk_rn(p12, p13)};
                const short8_t pb = __builtin_bit_cast(short8_t, pu);
                o[t][0] = __builtin_amdgcn_mfma_f32_16x16x32_bf16(va0, pb, o[t][0], 0, 0, 0);
                o[t][1] = __builtin_amdgcn_mfma_f32_16x16x32_bf16(va1, pb, o[t][1], 0, 0, 0);
                lacc[t] = __builtin_amdgcn_mfma_f32_16x16x32_bf16(ones, pb, lacc[t], 0, 0, 0);
            }
        }

        *(short8_t*)&Kt[p ^ 1][krow_s][koff_s]     = k0a;
        *(short8_t*)&Kt[p ^ 1][krow_s][koff_s + 8] = k0b;
        *(short8_t*)&Vt[p ^ 1][drow_s][voff_s]     = v0a;
        *(short8_t*)&Vt[p ^ 1][drow_s][voff_s + 8] = v0b;
    }

#pragma unroll
    for (int t = 0; t < 2; ++t) {
        const float inv = 1.f / lacc[t][0];
        float* op = qatt + (size_t)qrow[t] * CC + h * HD;
#pragma unroll
        for (int r = 0; r < 4; ++r) {
            op[quad * 4 + r]      = o[t][0][r] * inv;
            op[16 + quad * 4 + r] = o[t][1][r] * inv;
        }
    }
}

__global__ __launch_bounds__(256) void proj_lds(
    float* att, const float* __restrict__ wp, const float* __restrict__ bias)
{
    __shared__ __align__(16) unsigned short wt[CC * 40];
    const int mt = blockIdx.x, tid = threadIdx.x, wid = tid >> 6, lane = tid & 63;
    const int quad = lane >> 4, col = lane & 15;
    const int m0 = mt * 16;
    floatx4 acc[6];
#pragma unroll
    for (int j = 0; j < 6; ++j) acc[j] = (floatx4){0.f, 0.f, 0.f, 0.f};
    for (int kb = 0; kb < CC; kb += 32) {
        float gv[12][4];
#pragma unroll
        for (int g = 0; g < 12; ++g) {
            const int flat = tid + g * 256, n = flat % 384, kg = flat / 384;
#pragma unroll
            for (int j = 0; j < 4; ++j) gv[g][j] = wp[(size_t)(kb + kg * 4 + j) * CC + n];
        }
        __syncthreads();
#pragma unroll
        for (int g = 0; g < 12; ++g) {
            const int flat = tid + g * 256, n = flat % 384, kg = flat / 384;
            ushort4 u;
            u.x = f2bf(gv[g][0]); u.y = f2bf(gv[g][1]);
            u.z = f2bf(gv[g][2]); u.w = f2bf(gv[g][3]);
            *(ushort4*)&wt[n * 40 + kg * 4] = u;
        }
        __syncthreads();
        const float* ap = att + (size_t)(m0 + col) * CC + kb + quad * 8;
        const short8_t af = pack8(*(const float4*)ap, *(const float4*)(ap + 4));
#pragma unroll
        for (int j = 0; j < 6; ++j) {
            const short8_t pb = *(const short8_t*)&wt[(wid * 96 + j * 16 + col) * 40 + quad * 8];
            acc[j] = __builtin_amdgcn_mfma_f32_16x16x32_bf16(af, pb, acc[j], 0, 0, 0);
        }
    }
    __syncthreads();
#pragma unroll
    for (int j = 0; j < 6; ++j) {
        const int n = wid * 96 + j * 16 + col;
        const float bv = bias[n];
#pragma unroll
        for (int r = 0; r < 4; ++r)
            att[(size_t)(m0 + quad * 4 + r) * CC + n] = acc[j][r] + bv;
    }
}

__global__ void marker_kernel(float* out, float val, int nelem) {
    int i = blockIdx.x * 256 + threadIdx.x;
    if (i < nelem) out[i] = val;
}

// ---------------------------------------------------------------------------
extern "C" void kernel_launch(void* const* d_in, const int* in_sizes, int n_in,
                              void* d_out, int out_size, void* d_ws, size_t ws_size,
                              hipStream_t stream)
{
    const float* x     = (const float*)d_in[0];
    const float* wqkv  = (const float*)d_in[1];
    const float* wproj = (const float*)d_in[2];
    const float* bproj = (const float*)d_in[3];
    float* out = (float*)d_out;
    unsigned short* kv = (unsigned short*)d_ws;

    if (ws_size < KV_BYTES) {
        const float marker = 100.f + (float)(ws_size >> 20);
        marker_kernel<<<(out_size + 255) / 256, 256, 0, stream>>>(out, marker, out_size);
        return;
    }

    unsigned short* wqkvT  = kv + (size_t)2 * BB * NH * SEQ * HD;
    unsigned short* wprojT = wqkvT + (size_t)C3 * CC;
    unsigned short* xb     = wprojT + (size_t)CC * CC;   // doubles as ab

    if (ws_size >= KV_BYTES + WT_BYTES + XB_BYTES) {
        unsigned short* qb = (unsigned short*)d_out;      // bf16 Q in d_out
        prep_kernel<<<144 + 1536, 256, 0, stream>>>(x, wqkv, wproj, wqkvT, wprojT, xb);
        qkv_fast<<<576, 256, 0, stream>>>(xb, wqkvT, qb, kv);
        attn_kernel<<<16 * BB * NH, 256, 0, stream>>>(kv, qb, xb /*ab: xb dead*/);
        proj_fast<<<BB * SEQ / 32, 512, 0, stream>>>(xb, wprojT, bproj, out);
    } else {
        qkv_lds<<<576, 256, 0, stream>>>(x, wqkv, out, kv);
        attn_f32<<<16 * BB * NH, 256, 0, stream>>>(kv, out);
        proj_lds<<<BB * SEQ / 16, 256, 0, stream>>>(out, wproj, bproj);
    }
}